// Round 15
// baseline (179.720 us; speedup 1.0000x reference)
//
#include <hip/hip_runtime.h>
#include <math.h>

#define Bn 32
#define Hc 32
#define Ln 32768
#define RELC 2
#define IMC 4
#define OC 8
#define CATC 16
#define KS 7
#define NPOS (Bn*Ln)
#define TPB 256
#define VPT 4
#define PPB (TPB*VPT)          // 1024 positions per chunk
#define TILES (Ln/PPB)         // 32
#define NBLK (Bn*TILES)        // 1024 chunks
#define NSLOT 16
#define SSTR 128               // doubles per stat slot
// chunk strides (elements)
#define PCH (RELC*PPB)         // 2048  (phi / psi chunk)
#define BCH (OC*PPB)           // 8192  (beta / ag chunk)
#define XCH (Hc*PPB)           // 32768 (x chunk)

// slot-relative stat indices
#define iS_PHI  0
#define iSS_PHI 2
#define iS_PSI  4
#define iSS_PSI 6
#define iS_T    8
#define iSS_T   12
#define iS_AP   16
#define iSS_AP  24
#define iS_Y    32
#define iSS_Y   64
// bstats (psi boundary corrections, unslotted)
#define bPF  0
#define bPFS 6
#define bQL  12
#define bQLS 18
#define NBST 24
#define NZERO ((size_t)NSLOT*SSTR + NBST)   // doubles to zero

#define FMA4(A,S,V) { A.x=fmaf((S),(V).x,A.x); A.y=fmaf((S),(V).y,A.y); A.z=fmaf((S),(V).z,A.z); A.w=fmaf((S),(V).w,A.w); }

__device__ inline float4 affrelu(float4 v, float a, float d){
    float4 r;
    r.x=fmaxf(fmaf(a,v.x,d),0.f); r.y=fmaxf(fmaf(a,v.y,d),0.f);
    r.z=fmaxf(fmaf(a,v.z,d),0.f); r.w=fmaxf(fmaf(a,v.w,d),0.f);
    return r;
}
__device__ inline double wredd(double v){
    #pragma unroll
    for (int o=32;o>0;o>>=1) v += __shfl_down(v,o,64);
    return v;
}
__device__ inline float wredf(float v){
    #pragma unroll
    for (int o=32;o>0;o>>=1) v += __shfl_down(v,o,64);
    return v;
}
__device__ inline void atomAddD(double* p, double v){ unsafeAtomicAdd(p, v); }

// ---- bf16 helpers (RNE) ----
__device__ inline unsigned short f2b(float f){
    unsigned int u = __float_as_uint(f);
    u += 0x7FFFu + ((u>>16)&1u);
    return (unsigned short)(u>>16);
}
__device__ inline float b2f(unsigned short h){ return __uint_as_float(((unsigned int)h)<<16); }
__device__ inline ushort4 pack4r(float4 v, float4* r){
    ushort4 h;
    h.x=f2b(v.x); h.y=f2b(v.y); h.z=f2b(v.z); h.w=f2b(v.w);
    r->x=b2f(h.x); r->y=b2f(h.y); r->z=b2f(h.z); r->w=b2f(h.w);
    return h;
}
__device__ inline ushort4 pack4(float4 v){
    ushort4 h;
    h.x=f2b(v.x); h.y=f2b(v.y); h.z=f2b(v.z); h.w=f2b(v.w);
    return h;
}
__device__ inline float4 unpack4(ushort4 h){
    return make_float4(b2f(h.x),b2f(h.y),b2f(h.z),b2f(h.w));
}
typedef unsigned short us8 __attribute__((ext_vector_type(8)));
typedef float f4nt __attribute__((ext_vector_type(4)));
__device__ inline void ntstore4(float* p, float4 v){
    union { float4 a; f4nt b; } u; u.a = v;
    __builtin_nontemporal_store(u.b, (f4nt*)p);
}

// ---- parallel BN-affine computation ----
// channel map: [0,16)=cat, [16,20)=im, [20,28)=ag, [28,60)=hid
template<int NCH>
__device__ void affines(const double* __restrict__ stats, const double* __restrict__ bstats,
                        const float* g_cat, const float* be_cat,
                        const float* g_im,  const float* be_im,
                        const float* g_ag,  const float* be_ag,
                        const float* g_hid, const float* be_hid,
                        double (*redS)[16], double (*redQ)[16],
                        double* bstL, float* aAll, float* dAll, int tid)
{
    if (tid < NBST) bstL[tid] = bstats[tid];
    for (int p = tid; p < NCH*16; p += TPB){
        int ch = p >> 4, s = p & 15;
        int si, qi;
        if (ch < 2)       { si = iS_PHI+ch;           qi = iSS_PHI+ch; }
        else if (ch < 16) { int cp=(ch-2)/KS;         si = iS_PSI+cp;  qi = iSS_PSI+cp; }
        else if (ch < 20) { int i=ch-16;              si = iS_T+i;     qi = iSS_T+i; }
        else if (ch < 28) { int o=ch-20;              si = iS_AP+o;    qi = iSS_AP+o; }
        else              { int h=ch-28;              si = iS_Y+h;     qi = iSS_Y+h; }
        redS[ch][s] = stats[(size_t)s*SSTR + si];
        redQ[ch][s] = stats[(size_t)s*SSTR + qi];
    }
    __syncthreads();
    if (tid < NCH){
        double S=0, SS=0;
        #pragma unroll
        for (int s=0;s<16;++s){ S += redS[tid][s]; SS += redQ[tid][s]; }
        float g, be;
        if (tid < 16){
            if (tid >= 2){
                int cp=(tid-2)/KS, j=(tid-2)%KS, d=j-KS/2;
                if (d>0) for (int i=0;i<d;++i)   { S-=bstL[bPF+cp*3+i]; SS-=bstL[bPFS+cp*3+i]; }
                if (d<0) for (int i=3+d;i<3;++i) { S-=bstL[bQL+cp*3+i]; SS-=bstL[bQLS+cp*3+i]; }
            }
            g=g_cat[tid]; be=be_cat[tid];
        } else if (tid < 20){ g=g_im[tid-16]; be=be_im[tid-16]; }
        else if (tid < 28){ g=g_ag[tid-20]; be=be_ag[tid-20]; }
        else { g=g_hid[tid-28]; be=be_hid[tid-28]; }
        const double N=(double)NPOS;
        double m=S/N, v=SS/N-m*m, inv=1.0/sqrt(v+1e-5);
        aAll[tid]=(float)(g*inv);
        dAll[tid]=be-(float)(m*inv*g);
    }
}

// =================== k0: contiguous half-row read -> chunk-scatter xC; + zero stats ===================
__global__ void __launch_bounds__(TPB) k0(const float* __restrict__ x, unsigned short* __restrict__ xC,
                                          double* __restrict__ statz)
{
    if (blockIdx.x == 0){
        for (size_t i = threadIdx.x; i < NZERO; i += TPB) statz[i] = 0.0;
    }
    const int rr = blockIdx.x;              // 2048 half-rows
    const int r  = rr >> 1;                 // b*Hc + h
    const int half = rr & 1;
    const int b = r >> 5, h = r & 31;
    const float* src = x + (size_t)r*Ln + (size_t)half*(Ln/2);
    unsigned short* dstBase = xC + (size_t)b*TILES*XCH + (size_t)(half*(TILES/2))*XCH
                               + (size_t)h*PPB + threadIdx.x*4;
    const float* s4 = src + threadIdx.x*4;
    #pragma unroll 4
    for (int t = 0; t < TILES/2; ++t){
        float4 v = *(const float4*)(s4 + (size_t)t*PPB);
        *(ushort4*)(dstBase + (size_t)t*XCH) = pack4(v);
    }
}

// =================== k1c: xC -> phiC,psiC,betaC (chunked bf16) + phi/psi stats ===================
__global__ void __launch_bounds__(TPB) k1c(
    const unsigned short* __restrict__ xC,
    const float* __restrict__ w_phi, const float* __restrict__ b_phi,
    const float* __restrict__ w_psi, const float* __restrict__ b_psi,
    const float* __restrict__ w_beta,const float* __restrict__ b_beta,
    unsigned short* __restrict__ phiC, unsigned short* __restrict__ psiC,
    unsigned short* __restrict__ betaC,
    double* __restrict__ stats, double* __restrict__ bstats)
{
    __shared__ __align__(16) float wl[Hc*12 + 12];
    __shared__ double rbuf[4][8];
    const int tid = threadIdx.x;
    for (int i = tid; i < Hc*12; i += TPB) {
        int h = i/12, j = i%12;
        float v;
        if (j < 2)      v = w_phi[j*Hc + h];
        else if (j < 4) v = w_psi[(j-2)*Hc + h];
        else            v = w_beta[(j-4)*Hc + h];
        wl[h*12 + j] = v;
    }
    if (tid < 12)
        wl[Hc*12+tid] = (tid<2) ? b_phi[tid] : (tid<4) ? b_psi[tid-2] : b_beta[tid-4];
    __syncthreads();

    const int cidx = blockIdx.x;
    const int tile = cidx % TILES;
    const int li   = tid*VPT;
    double* st = stats + (size_t)(cidx & (NSLOT-1))*SSTR;

    float4 acc[12];
    #pragma unroll
    for (int j=0;j<12;++j){ float bb = wl[Hc*12+j]; acc[j]=make_float4(bb,bb,bb,bb); }

    const unsigned short* xb = xC + (size_t)cidx*XCH + li;
    #pragma unroll
    for (int g=0; g<4; ++g){
        ushort4 xv[8];
        #pragma unroll
        for (int j=0;j<8;++j) xv[j] = *(const ushort4*)(xb + (size_t)(g*8+j)*PPB);
        #pragma unroll
        for (int j=0;j<8;++j){
            const int h = g*8+j;
            const float4 x4 = unpack4(xv[j]);
            const float4 w0 = *(const float4*)(&wl[h*12+0]);
            const float4 w1 = *(const float4*)(&wl[h*12+4]);
            const float4 w2 = *(const float4*)(&wl[h*12+8]);
            FMA4(acc[0],w0.x,x4); FMA4(acc[1],w0.y,x4); FMA4(acc[2],w0.z,x4); FMA4(acc[3],w0.w,x4);
            FMA4(acc[4],w1.x,x4); FMA4(acc[5],w1.y,x4); FMA4(acc[6],w1.z,x4); FMA4(acc[7],w1.w,x4);
            FMA4(acc[8],w2.x,x4); FMA4(acc[9],w2.y,x4); FMA4(acc[10],w2.z,x4); FMA4(acc[11],w2.w,x4);
        }
    }
    float4 rphi[2], rpsi[2];
    #pragma unroll
    for (int c=0;c<RELC;++c){
        ushort4 hp = pack4r(acc[c], &rphi[c]);
        *(ushort4*)(phiC + (size_t)cidx*PCH + c*PPB + li) = hp;
        ushort4 hq = pack4r(acc[2+c], &rpsi[c]);
        *(ushort4*)(psiC + (size_t)cidx*PCH + c*PPB + li) = hq;
    }
    #pragma unroll
    for (int o=0;o<OC;++o)
        *(ushort4*)(betaC + (size_t)cidx*BCH + o*PPB + li) = pack4(acc[4+o]);

    double vals[8];
    #pragma unroll
    for (int c=0;c<2;++c){
        float4 v = rphi[c];
        vals[c]   = (double)v.x+v.y+v.z+v.w;
        vals[2+c] = (double)v.x*v.x+(double)v.y*v.y+(double)v.z*v.z+(double)v.w*v.w;
        float4 u = rpsi[c];
        vals[4+c] = (double)u.x+u.y+u.z+u.w;
        vals[6+c] = (double)u.x*u.x+(double)u.y*u.y+(double)u.z*u.z+(double)u.w*u.w;
    }
    if (tile==0 || tile==TILES-1) {
        #pragma unroll
        for (int c=0;c<2;++c){
            const float pv[4] = {rpsi[c].x, rpsi[c].y, rpsi[c].z, rpsi[c].w};
            #pragma unroll
            for (int e=0;e<4;++e){
                int le = tile*PPB + li + e;
                if (le < 3) {
                    atomAddD(&bstats[bPF +c*3+le], (double)pv[e]);
                    atomAddD(&bstats[bPFS+c*3+le], (double)pv[e]*pv[e]);
                }
                if (le >= Ln-3) {
                    int i = le-(Ln-3);
                    atomAddD(&bstats[bQL +c*3+i], (double)pv[e]);
                    atomAddD(&bstats[bQLS+c*3+i], (double)pv[e]*pv[e]);
                }
            }
        }
    }
    const int lane=tid&63, wid=tid>>6;
    #pragma unroll
    for (int i=0;i<8;++i){ double r=wredd(vals[i]); if(lane==0) rbuf[wid][i]=r; }
    __syncthreads();
    if (tid<8) atomAddD(&st[iS_PHI+tid], rbuf[0][tid]+rbuf[1][tid]+rbuf[2][tid]+rbuf[3][tid]);
}

// helper: vectorized psi staging (chunked bf16 -> f32 LDS); idx 0..1029 = pos lb-3+idx
#define STAGE_PSI_V(psiT)                                                                  \
    {                                                                                      \
        int c_ = tid >> 7, k_ = tid & 127;                                                 \
        us8 v_ = *(const us8*)(psiC + (size_t)cidx*PCH + c_*PPB + 8*k_);                   \
        _Pragma("unroll")                                                                  \
        for (int j_=0;j_<8;++j_) psiT[c_][3+8*k_+j_] = b2f(v_[j_]);                        \
        if (tid < 6){ int cc=tid/3, ii=tid%3;                                              \
            psiT[cc][ii] = (tile>0) ? b2f(psiC[(size_t)(cidx-1)*PCH + cc*PPB + 1021+ii]) : 0.f; }\
        else if (tid < 12){ int kk=tid-6, cc=kk/3, ii=kk%3;                                \
            psiT[cc][1027+ii] = (tile<TILES-1) ? b2f(psiC[(size_t)(cidx+1)*PCH + cc*PPB + ii]) : 0.f; } \
    }

// helper: compute tacc[IMC] (float4 each) from chunked bf16 phi + psiT
#define COMPUTE_T(tacc,aCat,dCat,w1s,b1s,psiT)                                             \
    _Pragma("unroll")                                                                      \
    for (int o=0;o<IMC;++o){ float bb=b1s[o]; tacc[o]=make_float4(bb,bb,bb,bb); }          \
    _Pragma("unroll")                                                                      \
    for (int c=0;c<RELC;++c){                                                              \
        float4 pv = unpack4(*(const ushort4*)(phiC + (size_t)cidx*PCH + c*PPB + li));      \
        float4 hv = affrelu(pv, aCat[c], dCat[c]);                                         \
        _Pragma("unroll")                                                                  \
        for (int o=0;o<IMC;++o) FMA4(tacc[o], w1s[o*CATC+c], hv);                          \
    }                                                                                      \
    _Pragma("unroll")                                                                      \
    for (int c=0;c<RELC;++c){                                                              \
        float4 A  = *(const float4*)&psiT[c][li];                                          \
        float4 Bv = *(const float4*)&psiT[c][li+4];                                        \
        float4 Cv = *(const float4*)&psiT[c][li+8];                                        \
        float pr[12] = {A.x,A.y,A.z,A.w, Bv.x,Bv.y,Bv.z,Bv.w, Cv.x,Cv.y,Cv.z,Cv.w};        \
        _Pragma("unroll")                                                                  \
        for (int j=0;j<KS;++j){                                                            \
            int ch = 2 + c*KS + j;                                                         \
            float a=aCat[ch], d=dCat[ch];                                                  \
            float4 hv;                                                                     \
            hv.x=fmaxf(fmaf(a,pr[j+0],d),0.f);                                             \
            hv.y=fmaxf(fmaf(a,pr[j+1],d),0.f);                                             \
            hv.z=fmaxf(fmaf(a,pr[j+2],d),0.f);                                             \
            hv.w=fmaxf(fmaf(a,pr[j+3],d),0.f);                                             \
            _Pragma("unroll")                                                              \
            for (int o=0;o<IMC;++o) FMA4(tacc[o], w1s[o*CATC+ch], hv);                     \
        }                                                                                  \
    }

// helper: recompute ag[OC] from tacc + chunked bf16 beta
#define COMPUTE_AG(ag,tacc,aIm,dIm,aAg,dAg,w2s,b2s)                                        \
    {                                                                                      \
        float4 h2[IMC];                                                                    \
        _Pragma("unroll")                                                                  \
        for (int i=0;i<IMC;++i) h2[i]=affrelu(tacc[i],aIm[i],dIm[i]);                      \
        _Pragma("unroll")                                                                  \
        for (int o=0;o<OC;++o){                                                            \
            float bb=b2s[o];                                                               \
            float4 w=make_float4(bb,bb,bb,bb);                                             \
            _Pragma("unroll")                                                              \
            for (int i=0;i<IMC;++i) FMA4(w,w2s[o*IMC+i],h2[i]);                            \
            float4 bv = unpack4(*(const ushort4*)(betaC + (size_t)cidx*BCH + o*PPB + li)); \
            float4 av; av.x=w.x*bv.x; av.y=w.y*bv.y; av.z=w.z*bv.z; av.w=w.w*bv.w;         \
            ag[o]=affrelu(av, aAg[o], dAg[o]);                                             \
        }                                                                                  \
    }

// =================== k3t: t-stats only (512 blocks x 2 chunks) ===================
__global__ void __launch_bounds__(TPB) k3t(
    const unsigned short* __restrict__ phiC, const unsigned short* __restrict__ psiC,
    const float* __restrict__ w_cw1, const float* __restrict__ b_cw1,
    const float* __restrict__ g_cat, const float* __restrict__ be_cat,
    double* __restrict__ stats, const double* __restrict__ bstats)
{
    __shared__ float w1s[IMC*CATC], b1s[IMC];
    __shared__ __align__(16) float psiT[2][1032];
    __shared__ double rbuf[4][8];
    __shared__ double redS[16][16], redQ[16][16];
    __shared__ double bstL[NBST];
    __shared__ float aAll[16], dAll[16];
    const int tid = threadIdx.x;
    const int li   = tid*VPT;

    if (tid < IMC*CATC) w1s[tid] = w_cw1[tid];
    if (tid < IMC)      b1s[tid] = b_cw1[tid];
    affines<16>(stats,bstats, g_cat,be_cat, 0,0, 0,0, 0,0, redS,redQ,bstL,aAll,dAll, tid);

    double vals[8] = {0,0,0,0,0,0,0,0};
    for (int sub=0; sub<2; ++sub){
        const int cidx = blockIdx.x*2 + sub;
        const int tile = cidx % TILES;
        __syncthreads();
        STAGE_PSI_V(psiT)
        __syncthreads();

        float4 tacc[IMC];
        COMPUTE_T(tacc,aAll,dAll,w1s,b1s,psiT)
        #pragma unroll
        for (int o=0;o<IMC;++o){
            float4 v = tacc[o];
            vals[o]   += (double)v.x+v.y+v.z+v.w;
            vals[4+o] += (double)v.x*v.x+(double)v.y*v.y+(double)v.z*v.z+(double)v.w*v.w;
        }
    }
    const int lane=tid&63, wid=tid>>6;
    #pragma unroll
    for (int i=0;i<8;++i){ double r=wredd(vals[i]); if(lane==0) rbuf[wid][i]=r; }
    __syncthreads();
    double* st = stats + (size_t)(blockIdx.x & (NSLOT-1))*SSTR;
    if (tid<8) atomAddD(&st[iS_T+tid], rbuf[0][tid]+rbuf[1][tid]+rbuf[2][tid]+rbuf[3][tid]);
}

// =================== k5a: recompute t -> ap-stats (512 blocks x 2 chunks) ===================
__global__ void __launch_bounds__(TPB) k5a(
    const unsigned short* __restrict__ phiC, const unsigned short* __restrict__ psiC,
    const unsigned short* __restrict__ betaC,
    const float* __restrict__ w_cw1, const float* __restrict__ b_cw1,
    const float* __restrict__ w_cw2, const float* __restrict__ b_cw2,
    const float* __restrict__ g_cat, const float* __restrict__ be_cat,
    const float* __restrict__ g_im,  const float* __restrict__ be_im,
    double* __restrict__ stats, const double* __restrict__ bstats)
{
    __shared__ float w1s[IMC*CATC], b1s[IMC], w2s[OC*IMC], b2s[OC];
    __shared__ __align__(16) float psiT[2][1032];
    __shared__ double rbuf[4][16];
    __shared__ double redS[20][16], redQ[20][16];
    __shared__ double bstL[NBST];
    __shared__ float aAll[20], dAll[20];
    const int tid = threadIdx.x;
    const int li   = tid*VPT;

    if (tid < IMC*CATC) w1s[tid] = w_cw1[tid];
    if (tid < IMC)      b1s[tid] = b_cw1[tid];
    if (tid>=64 && tid<64+OC*IMC) w2s[tid-64]=w_cw2[tid-64];
    if (tid>=96 && tid<96+OC)     b2s[tid-96]=b_cw2[tid-96];
    affines<20>(stats,bstats, g_cat,be_cat, g_im,be_im, 0,0, 0,0, redS,redQ,bstL,aAll,dAll, tid);

    double vals[16];
    #pragma unroll
    for (int i=0;i<16;++i) vals[i]=0.0;

    for (int sub=0; sub<2; ++sub){
        const int cidx = blockIdx.x*2 + sub;
        const int tile = cidx % TILES;
        __syncthreads();
        STAGE_PSI_V(psiT)
        __syncthreads();

        float4 tacc[IMC];
        COMPUTE_T(tacc,aAll,dAll,w1s,b1s,psiT)
        float4 h2[IMC];
        #pragma unroll
        for (int i=0;i<IMC;++i) h2[i]=affrelu(tacc[i],aAll[16+i],dAll[16+i]);
        #pragma unroll
        for (int o=0;o<OC;++o){
            float bb=b2s[o];
            float4 w=make_float4(bb,bb,bb,bb);
            #pragma unroll
            for (int i=0;i<IMC;++i) FMA4(w,w2s[o*IMC+i],h2[i]);
            float4 bv = unpack4(*(const ushort4*)(betaC + (size_t)cidx*BCH + o*PPB + li));
            float4 av; av.x=w.x*bv.x; av.y=w.y*bv.y; av.z=w.z*bv.z; av.w=w.w*bv.w;
            vals[o]   += (double)av.x+av.y+av.z+av.w;
            vals[8+o] += (double)av.x*av.x+(double)av.y*av.y+(double)av.z*av.z+(double)av.w*av.w;
        }
    }
    const int lane=tid&63, wid=tid>>6;
    #pragma unroll
    for (int i=0;i<16;++i){ double r=wredd(vals[i]); if(lane==0) rbuf[wid][i]=r; }
    __syncthreads();
    double* st = stats + (size_t)(blockIdx.x & (NSLOT-1))*SSTR;
    if (tid<16) atomAddD(&st[iS_AP+tid], rbuf[0][tid]+rbuf[1][tid]+rbuf[2][tid]+rbuf[3][tid]);
}

// =================== k7y: recompute -> ag (store agC); + x -> y-stats (512 x 2 chunks) ===================
__global__ void __launch_bounds__(TPB) k7y(
    const unsigned short* __restrict__ xC,
    const unsigned short* __restrict__ phiC, const unsigned short* __restrict__ psiC,
    const unsigned short* __restrict__ betaC, unsigned short* __restrict__ agC,
    const float* __restrict__ w_cw1, const float* __restrict__ b_cw1,
    const float* __restrict__ w_cw2, const float* __restrict__ b_cw2,
    const float* __restrict__ w_out, const float* __restrict__ b_out,
    const float* __restrict__ g_cat, const float* __restrict__ be_cat,
    const float* __restrict__ g_im,  const float* __restrict__ be_im,
    const float* __restrict__ g_ag,  const float* __restrict__ be_ag,
    double* __restrict__ stats, const double* __restrict__ bstats)
{
    __shared__ float w1s[IMC*CATC], b1s[IMC], w2s[OC*IMC], b2s[OC];
    __shared__ __align__(16) float wos[Hc*OC];
    __shared__ float bos[Hc];
    __shared__ __align__(16) float psiT[2][1032];
    __shared__ float fredS[Hc][4], fredQ[Hc][4];
    __shared__ double redS[28][16], redQ[28][16];
    __shared__ double bstL[NBST];
    __shared__ float aAll[28], dAll[28];
    const int tid = threadIdx.x;
    const int li   = tid*VPT;

    if (tid < IMC*CATC) w1s[tid] = w_cw1[tid];
    if (tid < IMC)      b1s[tid] = b_cw1[tid];
    if (tid>=64 && tid<64+OC*IMC) w2s[tid-64]=w_cw2[tid-64];
    if (tid>=96 && tid<96+OC)     b2s[tid-96]=b_cw2[tid-96];
    wos[tid] = w_out[tid];                                  // Hc*OC == 256
    if (tid>=128 && tid<128+Hc) bos[tid-128]=b_out[tid-128];
    affines<28>(stats,bstats, g_cat,be_cat, g_im,be_im, g_ag,be_ag, 0,0,
                redS,redQ,bstL,aAll,dAll, tid);

    const int lane=tid&63, wid=tid>>6;
    for (int sub=0; sub<2; ++sub){
        const int cidx = blockIdx.x*2 + sub;
        const int tile = cidx % TILES;
        __syncthreads();
        STAGE_PSI_V(psiT)
        __syncthreads();

        float4 tacc[IMC];
        COMPUTE_T(tacc,aAll,dAll,w1s,b1s,psiT)
        float4 ag[OC];
        COMPUTE_AG(ag,tacc,(aAll+16),(dAll+16),(aAll+20),(dAll+20),w2s,b2s)
        // round ag to bf16, store chunked; y-stats below use the ROUNDED values
        #pragma unroll
        for (int o=0;o<OC;++o){
            ushort4 hh = pack4r(ag[o], &ag[o]);
            *(ushort4*)(agC + (size_t)cidx*BCH + o*PPB + li) = hh;
        }

        const unsigned short* xb = xC + (size_t)cidx*XCH + li;
        #pragma unroll
        for (int g=0; g<4; ++g){
            ushort4 xv[8];
            #pragma unroll
            for (int j=0;j<8;++j) xv[j] = *(const ushort4*)(xb + (size_t)(g*8+j)*PPB);
            #pragma unroll
            for (int j=0;j<8;++j){
                const int h = g*8+j;
                float4 y = unpack4(xv[j]);
                float bb=bos[h]; y.x+=bb; y.y+=bb; y.z+=bb; y.w+=bb;
                #pragma unroll
                for (int o=0;o<OC;++o) FMA4(y, wos[h*OC+o], ag[o]);
                float fs=y.x+y.y+y.z+y.w;
                float fq=y.x*y.x+y.y*y.y+y.z*y.z+y.w*y.w;
                fs=wredf(fs); fq=wredf(fq);
                if (lane==0){
                    if (sub==0){ fredS[h][wid]=fs; fredQ[h][wid]=fq; }
                    else       { fredS[h][wid]+=fs; fredQ[h][wid]+=fq; }
                }
            }
        }
    }
    __syncthreads();
    double* st = stats + (size_t)(blockIdx.x & (NSLOT-1))*SSTR;
    if (tid<Hc){
        double s=(double)fredS[tid][0]+fredS[tid][1]+fredS[tid][2]+fredS[tid][3];
        double q=(double)fredQ[tid][0]+fredQ[tid][1]+fredQ[tid][2]+fredQ[tid][3];
        atomAddD(&st[iS_Y +tid], s);
        atomAddD(&st[iSS_Y+tid], q);
    }
}

// =================== k9s: xC + agC -> out (hid affine only, NT stores; 512 x 2 chunks) ===================
__global__ void __launch_bounds__(TPB) k9s(
    const unsigned short* __restrict__ xC, const unsigned short* __restrict__ agC,
    const float* __restrict__ w_out, const float* __restrict__ b_out,
    const float* __restrict__ g_hid, const float* __restrict__ be_hid,
    float* __restrict__ out, const double* __restrict__ stats)
{
    __shared__ double redS[Hc][16], redQ[Hc][16];
    __shared__ float aH[Hc], dH[Hc];
    __shared__ __align__(16) float wos[Hc*OC];
    __shared__ float bos[Hc];
    const int tid = threadIdx.x;
    const int li   = tid*VPT;

    wos[tid] = w_out[tid];
    if (tid>=128 && tid<128+Hc) bos[tid-128]=b_out[tid-128];
    for (int p = tid; p < Hc*16; p += TPB){
        int ch = p >> 4, s = p & 15;
        redS[ch][s] = stats[(size_t)s*SSTR + iS_Y + ch];
        redQ[ch][s] = stats[(size_t)s*SSTR + iSS_Y + ch];
    }
    __syncthreads();
    if (tid < Hc){
        double S=0, SS=0;
        #pragma unroll
        for (int s=0;s<16;++s){ S += redS[tid][s]; SS += redQ[tid][s]; }
        const double N=(double)NPOS;
        double m=S/N, v=SS/N-m*m, inv=1.0/sqrt(v+1e-5);
        aH[tid]=(float)(g_hid[tid]*inv);
        dH[tid]=be_hid[tid]-(float)(m*inv*g_hid[tid]);
    }
    __syncthreads();

    for (int sub=0; sub<2; ++sub){
        const int cidx = blockIdx.x*2 + sub;
        const int b    = cidx / TILES;
        const int tile = cidx % TILES;

        float4 ag[OC];
        {
            ushort4 av[OC];
            #pragma unroll
            for (int o=0;o<OC;++o) av[o] = *(const ushort4*)(agC + (size_t)cidx*BCH + o*PPB + li);
            #pragma unroll
            for (int o=0;o<OC;++o) ag[o] = unpack4(av[o]);
        }
        const unsigned short* xb = xC + (size_t)cidx*XCH + li;
        float* ob = out + (size_t)b*Hc*Ln + (size_t)tile*PPB + li;
        #pragma unroll
        for (int g=0; g<4; ++g){
            ushort4 xv[8];
            #pragma unroll
            for (int j=0;j<8;++j) xv[j] = *(const ushort4*)(xb + (size_t)(g*8+j)*PPB);
            #pragma unroll
            for (int j=0;j<8;++j){
                const int h = g*8+j;
                float4 y = unpack4(xv[j]);
                float bb=bos[h]; y.x+=bb; y.y+=bb; y.z+=bb; y.w+=bb;
                #pragma unroll
                for (int o=0;o<OC;++o) FMA4(y, wos[h*OC+o], ag[o]);
                ntstore4(ob + (size_t)h*Ln, affrelu(y, aH[h], dH[h]));
            }
        }
    }
}

extern "C" void kernel_launch(void* const* d_in, const int* in_sizes, int n_in,
                              void* d_out, int out_size, void* d_ws, size_t ws_size,
                              hipStream_t stream)
{
    const float* x     =(const float*)d_in[0];
    const float* w_phi =(const float*)d_in[1];  const float* b_phi =(const float*)d_in[2];
    const float* w_psi =(const float*)d_in[3];  const float* b_psi =(const float*)d_in[4];
    const float* w_beta=(const float*)d_in[5];  const float* b_beta=(const float*)d_in[6];
    const float* w_cw1 =(const float*)d_in[7];  const float* b_cw1 =(const float*)d_in[8];
    const float* w_cw2 =(const float*)d_in[9];  const float* b_cw2 =(const float*)d_in[10];
    const float* w_out =(const float*)d_in[11]; const float* b_out =(const float*)d_in[12];
    const float* g_cat =(const float*)d_in[13]; const float* be_cat=(const float*)d_in[14];
    const float* g_im  =(const float*)d_in[15]; const float* be_im =(const float*)d_in[16];
    const float* g_ag  =(const float*)d_in[17]; const float* be_ag =(const float*)d_in[18];
    const float* g_hid =(const float*)d_in[19]; const float* be_hid=(const float*)d_in[20];

    double* stats  = (double*)d_ws;
    double* bstats = stats + (size_t)NSLOT*SSTR;
    unsigned short* base = (unsigned short*)((char*)d_ws + 32768);
    unsigned short* phiC  = base;                              // 1024 chunks * 2048
    unsigned short* psiC  = phiC  + (size_t)NBLK*PCH;          // 1024 * 2048
    unsigned short* betaC = psiC  + (size_t)NBLK*PCH;          // 1024 * 8192
    unsigned short* xC    = betaC + (size_t)NBLK*BCH;          // 1024 * 32768
    unsigned short* agC   = xC    + (size_t)NBLK*XCH;          // 1024 * 8192

    k0 <<<Bn*Hc*2, TPB, 0, stream>>>(x, xC, stats);
    k1c<<<NBLK,   TPB, 0, stream>>>(xC, w_phi,b_phi, w_psi,b_psi, w_beta,b_beta,
                                    phiC,psiC,betaC, stats,bstats);
    k3t<<<NBLK/2, TPB, 0, stream>>>(phiC,psiC, w_cw1,b_cw1, g_cat,be_cat, stats,bstats);
    k5a<<<NBLK/2, TPB, 0, stream>>>(phiC,psiC,betaC, w_cw1,b_cw1, w_cw2,b_cw2,
                                    g_cat,be_cat, g_im,be_im, stats,bstats);
    k7y<<<NBLK/2, TPB, 0, stream>>>(xC, phiC,psiC,betaC, agC, w_cw1,b_cw1, w_cw2,b_cw2,
                                    w_out,b_out, g_cat,be_cat, g_im,be_im, g_ag,be_ag,
                                    stats,bstats);
    k9s<<<NBLK/2, TPB, 0, stream>>>(xC, agC, w_out,b_out, g_hid,be_hid,
                                    (float*)d_out, stats);
}

// Round 16
// 157.680 us; speedup vs baseline: 1.1398x; 1.1398x over previous
//
#include <hip/hip_runtime.h>
#include <math.h>

#define Bn 32
#define Hc 32
#define Ln 32768
#define RELC 2
#define IMC 4
#define OC 8
#define CATC 16
#define KS 7
#define NPOS (Bn*Ln)
#define TPB 256
#define VPT 4
#define PPB (TPB*VPT)          // 1024 positions per chunk
#define TILES (Ln/PPB)         // 32
#define NBLK (Bn*TILES)        // 1024 chunks
#define NSLOT 16
#define SSTR 128               // doubles per stat slot
// chunk strides (elements)
#define PCH (RELC*PPB)         // 2048  (phi / psi chunk)
#define BCH (OC*PPB)           // 8192  (beta / ag chunk)
#define XCH (Hc*PPB)           // 32768 (x chunk)

// slot-relative stat indices
#define iS_PHI  0
#define iSS_PHI 2
#define iS_PSI  4
#define iSS_PSI 6
#define iS_T    8
#define iSS_T   12
#define iS_AP   16
#define iSS_AP  24
#define iS_Y    32
#define iSS_Y   64
// bstats (psi boundary corrections, unslotted)
#define bPF  0
#define bPFS 6
#define bQL  12
#define bQLS 18
#define NBST 24
#define NZERO ((size_t)NSLOT*SSTR + NBST)   // doubles to zero

#define FMA4(A,S,V) { A.x=fmaf((S),(V).x,A.x); A.y=fmaf((S),(V).y,A.y); A.z=fmaf((S),(V).z,A.z); A.w=fmaf((S),(V).w,A.w); }

__device__ inline float4 affrelu(float4 v, float a, float d){
    float4 r;
    r.x=fmaxf(fmaf(a,v.x,d),0.f); r.y=fmaxf(fmaf(a,v.y,d),0.f);
    r.z=fmaxf(fmaf(a,v.z,d),0.f); r.w=fmaxf(fmaf(a,v.w,d),0.f);
    return r;
}
__device__ inline double wredd(double v){
    #pragma unroll
    for (int o=32;o>0;o>>=1) v += __shfl_down(v,o,64);
    return v;
}
__device__ inline float wredf(float v){
    #pragma unroll
    for (int o=32;o>0;o>>=1) v += __shfl_down(v,o,64);
    return v;
}
__device__ inline void atomAddD(double* p, double v){ unsafeAtomicAdd(p, v); }

// ---- bf16 helpers (RNE) ----
__device__ inline unsigned short f2b(float f){
    unsigned int u = __float_as_uint(f);
    u += 0x7FFFu + ((u>>16)&1u);
    return (unsigned short)(u>>16);
}
__device__ inline float b2f(unsigned short h){ return __uint_as_float(((unsigned int)h)<<16); }
__device__ inline ushort4 pack4r(float4 v, float4* r){
    ushort4 h;
    h.x=f2b(v.x); h.y=f2b(v.y); h.z=f2b(v.z); h.w=f2b(v.w);
    r->x=b2f(h.x); r->y=b2f(h.y); r->z=b2f(h.z); r->w=b2f(h.w);
    return h;
}
__device__ inline ushort4 pack4(float4 v){
    ushort4 h;
    h.x=f2b(v.x); h.y=f2b(v.y); h.z=f2b(v.z); h.w=f2b(v.w);
    return h;
}
__device__ inline float4 unpack4(ushort4 h){
    return make_float4(b2f(h.x),b2f(h.y),b2f(h.z),b2f(h.w));
}
typedef unsigned short us8 __attribute__((ext_vector_type(8)));
typedef float f4nt __attribute__((ext_vector_type(4)));
__device__ inline void ntstore4(float* p, float4 v){
    union { float4 a; f4nt b; } u; u.a = v;
    __builtin_nontemporal_store(u.b, (f4nt*)p);
}

// ---- parallel BN-affine computation ----
// channel map: [0,16)=cat, [16,20)=im, [20,28)=ag, [28,60)=hid
template<int NCH>
__device__ void affines(const double* __restrict__ stats, const double* __restrict__ bstats,
                        const float* g_cat, const float* be_cat,
                        const float* g_im,  const float* be_im,
                        const float* g_ag,  const float* be_ag,
                        const float* g_hid, const float* be_hid,
                        double (*redS)[16], double (*redQ)[16],
                        double* bstL, float* aAll, float* dAll, int tid)
{
    if (tid < NBST) bstL[tid] = bstats[tid];
    for (int p = tid; p < NCH*16; p += TPB){
        int ch = p >> 4, s = p & 15;
        int si, qi;
        if (ch < 2)       { si = iS_PHI+ch;           qi = iSS_PHI+ch; }
        else if (ch < 16) { int cp=(ch-2)/KS;         si = iS_PSI+cp;  qi = iSS_PSI+cp; }
        else if (ch < 20) { int i=ch-16;              si = iS_T+i;     qi = iSS_T+i; }
        else if (ch < 28) { int o=ch-20;              si = iS_AP+o;    qi = iSS_AP+o; }
        else              { int h=ch-28;              si = iS_Y+h;     qi = iSS_Y+h; }
        redS[ch][s] = stats[(size_t)s*SSTR + si];
        redQ[ch][s] = stats[(size_t)s*SSTR + qi];
    }
    __syncthreads();
    if (tid < NCH){
        double S=0, SS=0;
        #pragma unroll
        for (int s=0;s<16;++s){ S += redS[tid][s]; SS += redQ[tid][s]; }
        float g, be;
        if (tid < 16){
            if (tid >= 2){
                int cp=(tid-2)/KS, j=(tid-2)%KS, d=j-KS/2;
                if (d>0) for (int i=0;i<d;++i)   { S-=bstL[bPF+cp*3+i]; SS-=bstL[bPFS+cp*3+i]; }
                if (d<0) for (int i=3+d;i<3;++i) { S-=bstL[bQL+cp*3+i]; SS-=bstL[bQLS+cp*3+i]; }
            }
            g=g_cat[tid]; be=be_cat[tid];
        } else if (tid < 20){ g=g_im[tid-16]; be=be_im[tid-16]; }
        else if (tid < 28){ g=g_ag[tid-20]; be=be_ag[tid-20]; }
        else { g=g_hid[tid-28]; be=be_hid[tid-28]; }
        const double N=(double)NPOS;
        double m=S/N, v=SS/N-m*m, inv=1.0/sqrt(v+1e-5);
        aAll[tid]=(float)(g*inv);
        dAll[tid]=be-(float)(m*inv*g);
    }
}

// =================== k0: contiguous half-row read -> chunk-scatter xC; + zero stats ===================
__global__ void __launch_bounds__(TPB) k0(const float* __restrict__ x, unsigned short* __restrict__ xC,
                                          double* __restrict__ statz)
{
    if (blockIdx.x == 0){
        for (size_t i = threadIdx.x; i < NZERO; i += TPB) statz[i] = 0.0;
    }
    const int rr = blockIdx.x;              // 2048 half-rows
    const int r  = rr >> 1;                 // b*Hc + h
    const int half = rr & 1;
    const int b = r >> 5, h = r & 31;
    const float* src = x + (size_t)r*Ln + (size_t)half*(Ln/2);
    unsigned short* dstBase = xC + (size_t)b*TILES*XCH + (size_t)(half*(TILES/2))*XCH
                               + (size_t)h*PPB + threadIdx.x*4;
    const float* s4 = src + threadIdx.x*4;
    #pragma unroll 4
    for (int t = 0; t < TILES/2; ++t){
        float4 v = *(const float4*)(s4 + (size_t)t*PPB);
        *(ushort4*)(dstBase + (size_t)t*XCH) = pack4(v);
    }
}

// =================== k1c: xC -> phiC,psiC,betaC (chunked bf16) + phi/psi stats ===================
__global__ void __launch_bounds__(TPB) k1c(
    const unsigned short* __restrict__ xC,
    const float* __restrict__ w_phi, const float* __restrict__ b_phi,
    const float* __restrict__ w_psi, const float* __restrict__ b_psi,
    const float* __restrict__ w_beta,const float* __restrict__ b_beta,
    unsigned short* __restrict__ phiC, unsigned short* __restrict__ psiC,
    unsigned short* __restrict__ betaC,
    double* __restrict__ stats, double* __restrict__ bstats)
{
    __shared__ __align__(16) float wl[Hc*12 + 12];
    __shared__ double rbuf[4][8];
    const int tid = threadIdx.x;
    for (int i = tid; i < Hc*12; i += TPB) {
        int h = i/12, j = i%12;
        float v;
        if (j < 2)      v = w_phi[j*Hc + h];
        else if (j < 4) v = w_psi[(j-2)*Hc + h];
        else            v = w_beta[(j-4)*Hc + h];
        wl[h*12 + j] = v;
    }
    if (tid < 12)
        wl[Hc*12+tid] = (tid<2) ? b_phi[tid] : (tid<4) ? b_psi[tid-2] : b_beta[tid-4];
    __syncthreads();

    const int cidx = blockIdx.x;
    const int tile = cidx % TILES;
    const int li   = tid*VPT;
    double* st = stats + (size_t)(cidx & (NSLOT-1))*SSTR;

    float4 acc[12];
    #pragma unroll
    for (int j=0;j<12;++j){ float bb = wl[Hc*12+j]; acc[j]=make_float4(bb,bb,bb,bb); }

    const unsigned short* xb = xC + (size_t)cidx*XCH + li;
    #pragma unroll
    for (int g=0; g<4; ++g){
        ushort4 xv[8];
        #pragma unroll
        for (int j=0;j<8;++j) xv[j] = *(const ushort4*)(xb + (size_t)(g*8+j)*PPB);
        #pragma unroll
        for (int j=0;j<8;++j){
            const int h = g*8+j;
            const float4 x4 = unpack4(xv[j]);
            const float4 w0 = *(const float4*)(&wl[h*12+0]);
            const float4 w1 = *(const float4*)(&wl[h*12+4]);
            const float4 w2 = *(const float4*)(&wl[h*12+8]);
            FMA4(acc[0],w0.x,x4); FMA4(acc[1],w0.y,x4); FMA4(acc[2],w0.z,x4); FMA4(acc[3],w0.w,x4);
            FMA4(acc[4],w1.x,x4); FMA4(acc[5],w1.y,x4); FMA4(acc[6],w1.z,x4); FMA4(acc[7],w1.w,x4);
            FMA4(acc[8],w2.x,x4); FMA4(acc[9],w2.y,x4); FMA4(acc[10],w2.z,x4); FMA4(acc[11],w2.w,x4);
        }
    }
    float4 rphi[2], rpsi[2];
    #pragma unroll
    for (int c=0;c<RELC;++c){
        ushort4 hp = pack4r(acc[c], &rphi[c]);
        *(ushort4*)(phiC + (size_t)cidx*PCH + c*PPB + li) = hp;
        ushort4 hq = pack4r(acc[2+c], &rpsi[c]);
        *(ushort4*)(psiC + (size_t)cidx*PCH + c*PPB + li) = hq;
    }
    #pragma unroll
    for (int o=0;o<OC;++o)
        *(ushort4*)(betaC + (size_t)cidx*BCH + o*PPB + li) = pack4(acc[4+o]);

    double vals[8];
    #pragma unroll
    for (int c=0;c<2;++c){
        float4 v = rphi[c];
        vals[c]   = (double)v.x+v.y+v.z+v.w;
        vals[2+c] = (double)v.x*v.x+(double)v.y*v.y+(double)v.z*v.z+(double)v.w*v.w;
        float4 u = rpsi[c];
        vals[4+c] = (double)u.x+u.y+u.z+u.w;
        vals[6+c] = (double)u.x*u.x+(double)u.y*u.y+(double)u.z*u.z+(double)u.w*u.w;
    }
    if (tile==0 || tile==TILES-1) {
        #pragma unroll
        for (int c=0;c<2;++c){
            const float pv[4] = {rpsi[c].x, rpsi[c].y, rpsi[c].z, rpsi[c].w};
            #pragma unroll
            for (int e=0;e<4;++e){
                int le = tile*PPB + li + e;
                if (le < 3) {
                    atomAddD(&bstats[bPF +c*3+le], (double)pv[e]);
                    atomAddD(&bstats[bPFS+c*3+le], (double)pv[e]*pv[e]);
                }
                if (le >= Ln-3) {
                    int i = le-(Ln-3);
                    atomAddD(&bstats[bQL +c*3+i], (double)pv[e]);
                    atomAddD(&bstats[bQLS+c*3+i], (double)pv[e]*pv[e]);
                }
            }
        }
    }
    const int lane=tid&63, wid=tid>>6;
    #pragma unroll
    for (int i=0;i<8;++i){ double r=wredd(vals[i]); if(lane==0) rbuf[wid][i]=r; }
    __syncthreads();
    if (tid<8) atomAddD(&st[iS_PHI+tid], rbuf[0][tid]+rbuf[1][tid]+rbuf[2][tid]+rbuf[3][tid]);
}

// helper: vectorized psi staging (chunked bf16 -> f32 LDS); idx 0..1029 = pos lb-3+idx
#define STAGE_PSI_V(psiT)                                                                  \
    {                                                                                      \
        int c_ = tid >> 7, k_ = tid & 127;                                                 \
        us8 v_ = *(const us8*)(psiC + (size_t)cidx*PCH + c_*PPB + 8*k_);                   \
        _Pragma("unroll")                                                                  \
        for (int j_=0;j_<8;++j_) psiT[c_][3+8*k_+j_] = b2f(v_[j_]);                        \
        if (tid < 6){ int cc=tid/3, ii=tid%3;                                              \
            psiT[cc][ii] = (tile>0) ? b2f(psiC[(size_t)(cidx-1)*PCH + cc*PPB + 1021+ii]) : 0.f; }\
        else if (tid < 12){ int kk=tid-6, cc=kk/3, ii=kk%3;                                \
            psiT[cc][1027+ii] = (tile<TILES-1) ? b2f(psiC[(size_t)(cidx+1)*PCH + cc*PPB + ii]) : 0.f; } \
    }

// helper: compute tacc[IMC] (float4 each) from chunked bf16 phi + psiT
#define COMPUTE_T(tacc,aCat,dCat,w1s,b1s,psiT)                                             \
    _Pragma("unroll")                                                                      \
    for (int o=0;o<IMC;++o){ float bb=b1s[o]; tacc[o]=make_float4(bb,bb,bb,bb); }          \
    _Pragma("unroll")                                                                      \
    for (int c=0;c<RELC;++c){                                                              \
        float4 pv = unpack4(*(const ushort4*)(phiC + (size_t)cidx*PCH + c*PPB + li));      \
        float4 hv = affrelu(pv, aCat[c], dCat[c]);                                         \
        _Pragma("unroll")                                                                  \
        for (int o=0;o<IMC;++o) FMA4(tacc[o], w1s[o*CATC+c], hv);                          \
    }                                                                                      \
    _Pragma("unroll")                                                                      \
    for (int c=0;c<RELC;++c){                                                              \
        float4 A  = *(const float4*)&psiT[c][li];                                          \
        float4 Bv = *(const float4*)&psiT[c][li+4];                                        \
        float4 Cv = *(const float4*)&psiT[c][li+8];                                        \
        float pr[12] = {A.x,A.y,A.z,A.w, Bv.x,Bv.y,Bv.z,Bv.w, Cv.x,Cv.y,Cv.z,Cv.w};        \
        _Pragma("unroll")                                                                  \
        for (int j=0;j<KS;++j){                                                            \
            int ch = 2 + c*KS + j;                                                         \
            float a=aCat[ch], d=dCat[ch];                                                  \
            float4 hv;                                                                     \
            hv.x=fmaxf(fmaf(a,pr[j+0],d),0.f);                                             \
            hv.y=fmaxf(fmaf(a,pr[j+1],d),0.f);                                             \
            hv.z=fmaxf(fmaf(a,pr[j+2],d),0.f);                                             \
            hv.w=fmaxf(fmaf(a,pr[j+3],d),0.f);                                             \
            _Pragma("unroll")                                                              \
            for (int o=0;o<IMC;++o) FMA4(tacc[o], w1s[o*CATC+ch], hv);                     \
        }                                                                                  \
    }

// helper: recompute ag[OC] from tacc + chunked bf16 beta
#define COMPUTE_AG(ag,tacc,aIm,dIm,aAg,dAg,w2s,b2s)                                        \
    {                                                                                      \
        float4 h2[IMC];                                                                    \
        _Pragma("unroll")                                                                  \
        for (int i=0;i<IMC;++i) h2[i]=affrelu(tacc[i],aIm[i],dIm[i]);                      \
        _Pragma("unroll")                                                                  \
        for (int o=0;o<OC;++o){                                                            \
            float bb=b2s[o];                                                               \
            float4 w=make_float4(bb,bb,bb,bb);                                             \
            _Pragma("unroll")                                                              \
            for (int i=0;i<IMC;++i) FMA4(w,w2s[o*IMC+i],h2[i]);                            \
            float4 bv = unpack4(*(const ushort4*)(betaC + (size_t)cidx*BCH + o*PPB + li)); \
            float4 av; av.x=w.x*bv.x; av.y=w.y*bv.y; av.z=w.z*bv.z; av.w=w.w*bv.w;         \
            ag[o]=affrelu(av, aAg[o], dAg[o]);                                             \
        }                                                                                  \
    }

// =================== k3t: t-stats only (512 blocks x 2 chunks) ===================
__global__ void __launch_bounds__(TPB) k3t(
    const unsigned short* __restrict__ phiC, const unsigned short* __restrict__ psiC,
    const float* __restrict__ w_cw1, const float* __restrict__ b_cw1,
    const float* __restrict__ g_cat, const float* __restrict__ be_cat,
    double* __restrict__ stats, const double* __restrict__ bstats)
{
    __shared__ float w1s[IMC*CATC], b1s[IMC];
    __shared__ __align__(16) float psiT[2][1032];
    __shared__ double rbuf[4][8];
    __shared__ double redS[16][16], redQ[16][16];
    __shared__ double bstL[NBST];
    __shared__ float aAll[16], dAll[16];
    const int tid = threadIdx.x;
    const int li   = tid*VPT;

    if (tid < IMC*CATC) w1s[tid] = w_cw1[tid];
    if (tid < IMC)      b1s[tid] = b_cw1[tid];
    affines<16>(stats,bstats, g_cat,be_cat, 0,0, 0,0, 0,0, redS,redQ,bstL,aAll,dAll, tid);

    double vals[8] = {0,0,0,0,0,0,0,0};
    for (int sub=0; sub<2; ++sub){
        const int cidx = blockIdx.x*2 + sub;
        const int tile = cidx % TILES;
        __syncthreads();
        STAGE_PSI_V(psiT)
        __syncthreads();

        float4 tacc[IMC];
        COMPUTE_T(tacc,aAll,dAll,w1s,b1s,psiT)
        #pragma unroll
        for (int o=0;o<IMC;++o){
            float4 v = tacc[o];
            vals[o]   += (double)v.x+v.y+v.z+v.w;
            vals[4+o] += (double)v.x*v.x+(double)v.y*v.y+(double)v.z*v.z+(double)v.w*v.w;
        }
    }
    const int lane=tid&63, wid=tid>>6;
    #pragma unroll
    for (int i=0;i<8;++i){ double r=wredd(vals[i]); if(lane==0) rbuf[wid][i]=r; }
    __syncthreads();
    double* st = stats + (size_t)(blockIdx.x & (NSLOT-1))*SSTR;
    if (tid<8) atomAddD(&st[iS_T+tid], rbuf[0][tid]+rbuf[1][tid]+rbuf[2][tid]+rbuf[3][tid]);
}

// =================== k5a: recompute t -> ap-stats only ===================
__global__ void __launch_bounds__(TPB) k5a(
    const unsigned short* __restrict__ phiC, const unsigned short* __restrict__ psiC,
    const unsigned short* __restrict__ betaC,
    const float* __restrict__ w_cw1, const float* __restrict__ b_cw1,
    const float* __restrict__ w_cw2, const float* __restrict__ b_cw2,
    const float* __restrict__ g_cat, const float* __restrict__ be_cat,
    const float* __restrict__ g_im,  const float* __restrict__ be_im,
    double* __restrict__ stats, const double* __restrict__ bstats)
{
    __shared__ float w1s[IMC*CATC], b1s[IMC], w2s[OC*IMC], b2s[OC];
    __shared__ __align__(16) float psiT[2][1032];
    __shared__ double rbuf[4][16];
    __shared__ double redS[20][16], redQ[20][16];
    __shared__ double bstL[NBST];
    __shared__ float aAll[20], dAll[20];
    const int tid = threadIdx.x;
    const int cidx = blockIdx.x;
    const int tile = cidx % TILES;
    const int li   = tid*VPT;
    double* st = stats + (size_t)(cidx & (NSLOT-1))*SSTR;

    if (tid < IMC*CATC) w1s[tid] = w_cw1[tid];
    if (tid < IMC)      b1s[tid] = b_cw1[tid];
    if (tid>=64 && tid<64+OC*IMC) w2s[tid-64]=w_cw2[tid-64];
    if (tid>=96 && tid<96+OC)     b2s[tid-96]=b_cw2[tid-96];
    STAGE_PSI_V(psiT)
    affines<20>(stats,bstats, g_cat,be_cat, g_im,be_im, 0,0, 0,0, redS,redQ,bstL,aAll,dAll, tid);
    __syncthreads();

    float4 tacc[IMC];
    COMPUTE_T(tacc,aAll,dAll,w1s,b1s,psiT)

    double vals[16];
    {
        float4 h2[IMC];
        #pragma unroll
        for (int i=0;i<IMC;++i) h2[i]=affrelu(tacc[i],aAll[16+i],dAll[16+i]);
        #pragma unroll
        for (int o=0;o<OC;++o){
            float bb=b2s[o];
            float4 w=make_float4(bb,bb,bb,bb);
            #pragma unroll
            for (int i=0;i<IMC;++i) FMA4(w,w2s[o*IMC+i],h2[i]);
            float4 bv = unpack4(*(const ushort4*)(betaC + (size_t)cidx*BCH + o*PPB + li));
            float4 av; av.x=w.x*bv.x; av.y=w.y*bv.y; av.z=w.z*bv.z; av.w=w.w*bv.w;
            vals[o]   = (double)av.x+av.y+av.z+av.w;
            vals[8+o] = (double)av.x*av.x+(double)av.y*av.y+(double)av.z*av.z+(double)av.w*av.w;
        }
    }
    const int lane=tid&63, wid=tid>>6;
    #pragma unroll
    for (int i=0;i<16;++i){ double r=wredd(vals[i]); if(lane==0) rbuf[wid][i]=r; }
    __syncthreads();
    if (tid<16) atomAddD(&st[iS_AP+tid], rbuf[0][tid]+rbuf[1][tid]+rbuf[2][tid]+rbuf[3][tid]);
}

// =================== k7y: recompute -> ag (store agC); + chunked x -> y-stats ===================
__global__ void __launch_bounds__(TPB) k7y(
    const unsigned short* __restrict__ xC,
    const unsigned short* __restrict__ phiC, const unsigned short* __restrict__ psiC,
    const unsigned short* __restrict__ betaC, unsigned short* __restrict__ agC,
    const float* __restrict__ w_cw1, const float* __restrict__ b_cw1,
    const float* __restrict__ w_cw2, const float* __restrict__ b_cw2,
    const float* __restrict__ w_out, const float* __restrict__ b_out,
    const float* __restrict__ g_cat, const float* __restrict__ be_cat,
    const float* __restrict__ g_im,  const float* __restrict__ be_im,
    const float* __restrict__ g_ag,  const float* __restrict__ be_ag,
    double* __restrict__ stats, const double* __restrict__ bstats)
{
    __shared__ float w1s[IMC*CATC], b1s[IMC], w2s[OC*IMC], b2s[OC];
    __shared__ __align__(16) float wos[Hc*OC];
    __shared__ float bos[Hc];
    __shared__ __align__(16) float psiT[2][1032];
    __shared__ float fredS[Hc][4], fredQ[Hc][4];
    __shared__ double redS[28][16], redQ[28][16];
    __shared__ double bstL[NBST];
    __shared__ float aAll[28], dAll[28];
    const int tid = threadIdx.x;
    const int cidx = blockIdx.x;
    const int tile = cidx % TILES;
    const int li   = tid*VPT;
    double* st = stats + (size_t)(cidx & (NSLOT-1))*SSTR;

    if (tid < IMC*CATC) w1s[tid] = w_cw1[tid];
    if (tid < IMC)      b1s[tid] = b_cw1[tid];
    if (tid>=64 && tid<64+OC*IMC) w2s[tid-64]=w_cw2[tid-64];
    if (tid>=96 && tid<96+OC)     b2s[tid-96]=b_cw2[tid-96];
    wos[tid] = w_out[tid];                                  // Hc*OC == 256
    if (tid>=128 && tid<128+Hc) bos[tid-128]=b_out[tid-128];
    STAGE_PSI_V(psiT)
    affines<28>(stats,bstats, g_cat,be_cat, g_im,be_im, g_ag,be_ag, 0,0,
                redS,redQ,bstL,aAll,dAll, tid);
    __syncthreads();

    float4 tacc[IMC];
    COMPUTE_T(tacc,aAll,dAll,w1s,b1s,psiT)
    float4 ag[OC];
    COMPUTE_AG(ag,tacc,(aAll+16),(dAll+16),(aAll+20),(dAll+20),w2s,b2s)
    // round ag to bf16, store chunked; y-stats below use the ROUNDED values
    #pragma unroll
    for (int o=0;o<OC;++o){
        ushort4 hh = pack4r(ag[o], &ag[o]);
        *(ushort4*)(agC + (size_t)cidx*BCH + o*PPB + li) = hh;
    }

    const int lane=tid&63, wid=tid>>6;
    const unsigned short* xb = xC + (size_t)cidx*XCH + li;
    #pragma unroll
    for (int g=0; g<4; ++g){
        ushort4 xv[8];
        #pragma unroll
        for (int j=0;j<8;++j) xv[j] = *(const ushort4*)(xb + (size_t)(g*8+j)*PPB);
        #pragma unroll
        for (int j=0;j<8;++j){
            const int h = g*8+j;
            float4 y = unpack4(xv[j]);
            float bb=bos[h]; y.x+=bb; y.y+=bb; y.z+=bb; y.w+=bb;
            #pragma unroll
            for (int o=0;o<OC;++o) FMA4(y, wos[h*OC+o], ag[o]);
            float fs=y.x+y.y+y.z+y.w;
            float fq=y.x*y.x+y.y*y.y+y.z*y.z+y.w*y.w;
            fs=wredf(fs); fq=wredf(fq);
            if (lane==0){ fredS[h][wid]=fs; fredQ[h][wid]=fq; }
        }
    }
    __syncthreads();
    if (tid<Hc){
        double s=(double)fredS[tid][0]+fredS[tid][1]+fredS[tid][2]+fredS[tid][3];
        double q=(double)fredQ[tid][0]+fredQ[tid][1]+fredQ[tid][2]+fredQ[tid][3];
        atomAddD(&st[iS_Y +tid], s);
        atomAddD(&st[iSS_Y+tid], q);
    }
}

// =================== k9s: xC + agC -> out (hid affine only, NT stores) ===================
__global__ void __launch_bounds__(TPB) k9s(
    const unsigned short* __restrict__ xC, const unsigned short* __restrict__ agC,
    const float* __restrict__ w_out, const float* __restrict__ b_out,
    const float* __restrict__ g_hid, const float* __restrict__ be_hid,
    float* __restrict__ out, const double* __restrict__ stats)
{
    __shared__ double redS[Hc][16], redQ[Hc][16];
    __shared__ float aH[Hc], dH[Hc];
    __shared__ __align__(16) float wos[Hc*OC];
    __shared__ float bos[Hc];
    const int tid = threadIdx.x;
    const int cidx = blockIdx.x;
    const int b    = cidx / TILES;
    const int tile = cidx % TILES;
    const int li   = tid*VPT;

    wos[tid] = w_out[tid];
    if (tid>=128 && tid<128+Hc) bos[tid-128]=b_out[tid-128];
    for (int p = tid; p < Hc*16; p += TPB){
        int ch = p >> 4, s = p & 15;
        redS[ch][s] = stats[(size_t)s*SSTR + iS_Y + ch];
        redQ[ch][s] = stats[(size_t)s*SSTR + iSS_Y + ch];
    }
    __syncthreads();
    if (tid < Hc){
        double S=0, SS=0;
        #pragma unroll
        for (int s=0;s<16;++s){ S += redS[tid][s]; SS += redQ[tid][s]; }
        const double N=(double)NPOS;
        double m=S/N, v=SS/N-m*m, inv=1.0/sqrt(v+1e-5);
        aH[tid]=(float)(g_hid[tid]*inv);
        dH[tid]=be_hid[tid]-(float)(m*inv*g_hid[tid]);
    }
    __syncthreads();

    float4 ag[OC];
    {
        ushort4 av[OC];
        #pragma unroll
        for (int o=0;o<OC;++o) av[o] = *(const ushort4*)(agC + (size_t)cidx*BCH + o*PPB + li);
        #pragma unroll
        for (int o=0;o<OC;++o) ag[o] = unpack4(av[o]);
    }
    const unsigned short* xb = xC + (size_t)cidx*XCH + li;
    float* ob = out + (size_t)b*Hc*Ln + (size_t)tile*PPB + li;
    #pragma unroll
    for (int g=0; g<4; ++g){
        ushort4 xv[8];
        #pragma unroll
        for (int j=0;j<8;++j) xv[j] = *(const ushort4*)(xb + (size_t)(g*8+j)*PPB);
        #pragma unroll
        for (int j=0;j<8;++j){
            const int h = g*8+j;
            float4 y = unpack4(xv[j]);
            float bb=bos[h]; y.x+=bb; y.y+=bb; y.z+=bb; y.w+=bb;
            #pragma unroll
            for (int o=0;o<OC;++o) FMA4(y, wos[h*OC+o], ag[o]);
            ntstore4(ob + (size_t)h*Ln, affrelu(y, aH[h], dH[h]));
        }
    }
}

extern "C" void kernel_launch(void* const* d_in, const int* in_sizes, int n_in,
                              void* d_out, int out_size, void* d_ws, size_t ws_size,
                              hipStream_t stream)
{
    const float* x     =(const float*)d_in[0];
    const float* w_phi =(const float*)d_in[1];  const float* b_phi =(const float*)d_in[2];
    const float* w_psi =(const float*)d_in[3];  const float* b_psi =(const float*)d_in[4];
    const float* w_beta=(const float*)d_in[5];  const float* b_beta=(const float*)d_in[6];
    const float* w_cw1 =(const float*)d_in[7];  const float* b_cw1 =(const float*)d_in[8];
    const float* w_cw2 =(const float*)d_in[9];  const float* b_cw2 =(const float*)d_in[10];
    const float* w_out =(const float*)d_in[11]; const float* b_out =(const float*)d_in[12];
    const float* g_cat =(const float*)d_in[13]; const float* be_cat=(const float*)d_in[14];
    const float* g_im  =(const float*)d_in[15]; const float* be_im =(const float*)d_in[16];
    const float* g_ag  =(const float*)d_in[17]; const float* be_ag =(const float*)d_in[18];
    const float* g_hid =(const float*)d_in[19]; const float* be_hid=(const float*)d_in[20];

    double* stats  = (double*)d_ws;
    double* bstats = stats + (size_t)NSLOT*SSTR;
    unsigned short* base = (unsigned short*)((char*)d_ws + 32768);
    unsigned short* phiC  = base;                              // 1024 chunks * 2048
    unsigned short* psiC  = phiC  + (size_t)NBLK*PCH;          // 1024 * 2048
    unsigned short* betaC = psiC  + (size_t)NBLK*PCH;          // 1024 * 8192
    unsigned short* xC    = betaC + (size_t)NBLK*BCH;          // 1024 * 32768
    unsigned short* agC   = xC    + (size_t)NBLK*XCH;          // 1024 * 8192

    k0 <<<Bn*Hc*2, TPB, 0, stream>>>(x, xC, stats);
    k1c<<<NBLK,   TPB, 0, stream>>>(xC, w_phi,b_phi, w_psi,b_psi, w_beta,b_beta,
                                    phiC,psiC,betaC, stats,bstats);
    k3t<<<NBLK/2, TPB, 0, stream>>>(phiC,psiC, w_cw1,b_cw1, g_cat,be_cat, stats,bstats);
    k5a<<<NBLK,   TPB, 0, stream>>>(phiC,psiC,betaC, w_cw1,b_cw1, w_cw2,b_cw2,
                                    g_cat,be_cat, g_im,be_im, stats,bstats);
    k7y<<<NBLK,   TPB, 0, stream>>>(xC, phiC,psiC,betaC, agC, w_cw1,b_cw1, w_cw2,b_cw2,
                                    w_out,b_out, g_cat,be_cat, g_im,be_im, g_ag,be_ag,
                                    stats,bstats);
    k9s<<<NBLK,   TPB, 0, stream>>>(xC, agC, w_out,b_out, g_hid,be_hid,
                                    (float*)d_out, stats);
}